// Round 12
// baseline (69.145 us; speedup 1.0000x reference)
//
#include <hip/hip_runtime.h>
#include <hip/hip_bf16.h>

typedef __bf16 bf8 __attribute__((ext_vector_type(8)));
typedef float f32x4 __attribute__((ext_vector_type(4)));

#define NBINS 129
#define TROWS 16                 // rows per tile
#define MATB 8192                // bytes per mat per buffer (16 rows * 512B)
#define TAILB 512                // tail area: 2 mats * 16 rows * 16B
#define BUFB (2 * MATB + TAILB)  // 16896 B per buffer
#define GRID 768                 // 256 CUs * 3 blocks/CU, all persistent

__device__ __forceinline__ void gload_lds16(const float* src, char* ldsdst) {
    __builtin_amdgcn_global_load_lds(
        (const __attribute__((address_space(1))) void*)src,
        (__attribute__((address_space(3))) void*)ldsdst, 16, 0, 0);
}

__global__ __launch_bounds__(256, 3)
void irfft_mm(const float* __restrict__ re,
              const float* __restrict__ im,
              const float* __restrict__ mr,
              const float* __restrict__ mi,
              float* __restrict__ out,
              int ntiles)
{
    __shared__ __align__(16) char lds[3][BUFB];   // 50688 B -> 3 blocks/CU

    const int tid  = threadIdx.x;
    const int lane = tid & 63;
    const int w    = tid >> 6;   // wave id = output col-block (16 cols)
    const int r16  = lane & 15;
    const int q    = lane >> 4;
    const int rk   = r16 & 7;

    // ---- balanced contiguous tile range for this block ----
    const int qt  = ntiles / GRID;            // 20
    const int rt  = ntiles % GRID;            // 640
    const int bid = blockIdx.x;
    const int nit = qt + (bid < rt ? 1 : 0);  // 21 or 20
    const long t0 = (long)bid * qt + (bid < rt ? bid : rt);

    // staging geometry: wave w stages mat (w>>1), tile rows (w&1)*8 .. +7
    const int    smat  = w >> 1;
    const int    srow0 = (w & 1) * 8;
    const float* ssrc  = smat ? im : re;
    const int    lrow  = lane >> 5;   // 0/1: which of the 2 rows per instr
    const int    p     = lane & 31;   // linear 16B-chunk within row

    // ---- one batch = 5 VMEM ops per wave (4 row-stages + 1 masked tail-stage) ----
    #define STAGE(bn, rbn)                                                        \
        {                                                                         \
            char* _b = (bn);                                                      \
            const long _r = (rbn);                                                \
            _Pragma("unroll")                                                     \
            for (int i = 0; i < 4; ++i) {                                         \
                const int trow = srow0 + 2 * i + lrow;                            \
                const int g    = p ^ (trow & 7);   /* pre-swizzled global chunk */\
                gload_lds16(ssrc + (_r + trow) * (long)NBINS + g * 4,             \
                            _b + smat * MATB + (srow0 + 2 * i) * 512 + lane * 16);\
            }                                                                     \
            if (lane < 8)  /* k=128..131 tail chunk; only k=128 is consumed */    \
                gload_lds16(ssrc + (_r + srow0 + lane) * (long)NBINS + 128,       \
                            _b + 2 * MATB + smat * 256 + (srow0 + lane) * 16);    \
        }

    // ---- prologue: prime pipeline with tiles t0, t0+1 (nit >= 20 always) ----
    STAGE(lds[0], t0 * TROWS);
    STAGE(lds[1], (t0 + 1) * TROWS);

    // ---- A fragments (M^T cols w*16..+15) + f32 tail coefficients ----
    bf8 afr[2][4];
    #pragma unroll
    for (int m = 0; m < 2; ++m) {
        const float* M = m ? mi : mr;
        #pragma unroll
        for (int t = 0; t < 4; ++t) {
            bf8 a;
            #pragma unroll
            for (int j = 0; j < 8; ++j)
                a[j] = (__bf16)M[(t * 32 + q * 8 + j) * 64 + w * 16 + r16];
            afr[m][t] = a;
        }
    }
    const f32x4 mt0 = *(const f32x4*)(mr + 128 * 64 + w * 16 + q * 4);
    const f32x4 mt1 = *(const f32x4*)(mi + 128 * 64 + w * 16 + q * 4);

    int bi = 0;                                   // rotating buffer index
    for (int i = 0; i < nit; ++i) {
        char* bufc = lds[bi];
        const long rowbase = (t0 + i) * TROWS;

        // ---- counted wait: batch(i) landed; batch(i+1)'s 5 ops stay in flight ----
        __builtin_amdgcn_sched_barrier(0);
        if (i + 1 < nit) asm volatile("s_waitcnt vmcnt(5)" ::: "memory");
        else             asm volatile("s_waitcnt vmcnt(0)" ::: "memory");
        __builtin_amdgcn_s_barrier();
        __builtin_amdgcn_sched_barrier(0);

        // ---- issue batch(i+2): has TWO full periods to land ----
        if (i + 2 < nit) {
            int bi2 = bi + 2; if (bi2 >= 3) bi2 -= 3;
            STAGE(lds[bi2], (t0 + i + 2) * TROWS);
        }

        // ---- compute 16 rows x 16 cols per wave ----
        f32x4 acc = {0.0f, 0.0f, 0.0f, 0.0f};
        #pragma unroll
        for (int m = 0; m < 2; ++m) {
            const char* mb = bufc + m * MATB + r16 * 512;
            #pragma unroll
            for (int t = 0; t < 4; ++t) {
                const int j0 = t * 8 + q * 2;
                const f32x4 lo = *(const f32x4*)(mb + ((j0)     ^ rk) * 16);
                const f32x4 hi = *(const f32x4*)(mb + ((j0 + 1) ^ rk) * 16);
                bf8 bfr;
                #pragma unroll
                for (int jj = 0; jj < 4; ++jj) {
                    bfr[jj]     = (__bf16)lo[jj];
                    bfr[4 + jj] = (__bf16)hi[jj];
                }
                acc = __builtin_amdgcn_mfma_f32_16x16x32_bf16(afr[m][t], bfr, acc, 0, 0, 0);
            }
            // k = 128 rank-1 tail in exact f32 (from the DMA-staged tail area)
            const float xt = *(const float*)(bufc + 2 * MATB + m * 256 + r16 * 16);
            const f32x4 mt = m ? mt1 : mt0;
            #pragma unroll
            for (int jj = 0; jj < 4; ++jj) acc[jj] += xt * mt[jj];
        }

        // ---- coalesced f32x4 store ----
        *(f32x4*)(out + (rowbase + r16) * 64 + w * 16 + q * 4) = acc;

        bi = (bi == 2) ? 0 : bi + 1;
    }
    #undef STAGE
}

extern "C" void kernel_launch(void* const* d_in, const int* in_sizes, int n_in,
                              void* d_out, int out_size, void* d_ws, size_t ws_size,
                              hipStream_t stream)
{
    const float* re = (const float*)d_in[0];
    const float* im = (const float*)d_in[1];
    const float* mr = (const float*)d_in[2];
    const float* mi = (const float*)d_in[3];
    float* out = (float*)d_out;

    const long rows   = (long)in_sizes[0] / NBINS;   // 256000
    const int  ntiles = (int)(rows / TROWS);         // 16000
    irfft_mm<<<GRID, 256, 0, stream>>>(re, im, mr, mi, out, ntiles);
}